// Round 17
// baseline (93.218 us; speedup 1.0000x reference)
//
#include <hip/hip_runtime.h>
#include <hip/hip_bf16.h>

typedef __attribute__((ext_vector_type(8))) short bf16x8;
typedef __attribute__((ext_vector_type(4))) short bf16x4;
typedef __attribute__((ext_vector_type(4))) float f32x4;

#define NPW 4   // batches per wave

#define A3  0.33333334f
#define B4  0.25f
#define C34 0.28867513f

__device__ const int ADJ_IDX[16][4] = {
  {0,1,7,0},{1,0,2,8},{2,1,3,9},{3,2,4,10},
  {4,3,5,11},{5,4,6,12},{6,5,13,0},{7,0,8,0},
  {8,7,9,1},{9,8,10,2},{10,9,11,3},{11,10,12,4},
  {12,11,13,5},{13,12,6,0},{0,0,0,0},{0,0,0,0}
};
__device__ const float ADJ_W[16][4] = {
  {A3,C34,A3,0.f},{B4,C34,B4,B4},{B4,B4,B4,B4},{B4,B4,B4,B4},
  {B4,B4,B4,B4},{B4,B4,C34,B4},{A3,C34,A3,0.f},{A3,A3,C34,0.f},
  {B4,C34,B4,B4},{B4,B4,B4,B4},{B4,B4,B4,B4},{B4,B4,B4,B4},
  {B4,B4,C34,B4},{A3,C34,A3,0.f},{0.f,0.f,0.f,0.f},{0.f,0.f,0.f,0.f}
};

__device__ __forceinline__ unsigned short f2b(float x) {
  unsigned u = __builtin_bit_cast(unsigned, x);
  u += 0x7FFFu + ((u >> 16) & 1u);   // RNE bf16
  return (unsigned short)(u >> 16);
}
__device__ __forceinline__ unsigned pk2(float lo, float hi) {
  float2 t; t.x = lo; t.y = hi;
  __hip_bfloat162 h = __float22bfloat162_rn(t);
  unsigned u; __builtin_memcpy(&u, &h, 4);
  return u;
}
__device__ __forceinline__ bf16x4 mk4(unsigned lo, unsigned hi) {
  uint2 u; u.x = lo; u.y = hi;
  return __builtin_bit_cast(bf16x4, u);
}

#if __has_builtin(__builtin_amdgcn_mfma_f32_16x16x16_bf16)
#define MFMA16(a, b, c) __builtin_amdgcn_mfma_f32_16x16x16_bf16((a), (b), (c), 0, 0, 0)
#elif __has_builtin(__builtin_amdgcn_mfma_f32_16x16x16bf16_1k)
#define MFMA16(a, b, c) __builtin_amdgcn_mfma_f32_16x16x16bf16_1k((a), (b), (c), 0, 0, 0)
#else
__device__ __forceinline__ f32x4 mfma16_asm(bf16x4 a, bf16x4 b, f32x4 c) {
  f32x4 d;
  asm("v_mfma_f32_16x16x16_bf16 %0, %1, %2, %3\n\ts_nop 7\n\ts_nop 7"
      : "=v"(d) : "v"(a), "v"(b), "v"(c));
  return d;
}
#define MFMA16(a, b, c) mfma16_asm((a), (b), (c))
#endif

// ---------- weight prep (layouts unchanged) ----------
__global__ __launch_bounds__(256) void prep_w(
    const float* __restrict__ W1, const float* __restrict__ W2,
    unsigned short* __restrict__ wf)
{
  const int f = blockIdx.x * 256 + threadIdx.x;   // 20 blocks -> 5120
  if (f < 4096) {
    const int lane = f & 63, kk = (f >> 6) & 7, nt = f >> 9;
    const int col = nt * 16 + (lane & 15);
    const int k0  = kk * 32 + (lane >> 4) * 8;
    unsigned short tmp[8];
    #pragma unroll
    for (int j = 0; j < 8; ++j) tmp[j] = f2b(W1[(k0 + j) * 128 + col]);
    *(uint4*)(wf + (size_t)f * 8) = *(const uint4*)tmp;
  } else if (f < 5120) {
    const int f2i = f - 4096;                     // 0..1023
    const int lane = f2i & 63, kp = (f2i >> 6) & 3, nt = f2i >> 8;
    const int col = nt * 16 + (lane & 15);
    const int k0  = kp * 32 + (lane >> 4) * 4;
    uint4 q;
    q.x = (unsigned)f2b(W2[(k0 + 0) * 64 + col]) | ((unsigned)f2b(W2[(k0 + 1) * 64 + col]) << 16);
    q.y = (unsigned)f2b(W2[(k0 + 2) * 64 + col]) | ((unsigned)f2b(W2[(k0 + 3) * 64 + col]) << 16);
    q.z = (unsigned)f2b(W2[(k0 + 16) * 64 + col]) | ((unsigned)f2b(W2[(k0 + 17) * 64 + col]) << 16);
    q.w = (unsigned)f2b(W2[(k0 + 18) * 64 + col]) | ((unsigned)f2b(W2[(k0 + 19) * 64 + col]) << 16);
    *(uint4*)(wf + 32768 + (size_t)f2i * 8) = q;
  }
}

__global__ __launch_bounds__(512, 4) void fpm_kernel(
    const float* __restrict__ X,
    const unsigned short* __restrict__ wf,
    const float* __restrict__ b1, const float* __restrict__ b2,
    float* __restrict__ out, int Btot)
{
  __shared__ __align__(16) uint4 WL1[4096];   // 64 KiB W1 frags
  __shared__ __align__(16) uint4 WL2[1024];   // 16 KiB paired W2 frags
  // total 80 KiB: 2 blocks/CU co-reside (verified R14: occupancy 43%)

  const int tid  = threadIdx.x;
  const int lane = tid & 63;
  const int wv   = tid >> 6;
  const int lrow = lane & 15;
  const int lgrp = lane >> 4;

  const int gw    = blockIdx.x * 8 + wv;
  const int bbase = gw * NPW;
  const bool rowok = (lrow < 14);

  // ---- rolling X queue: 4 slots, each one kk-fragment (8 f32) ----
  float4 qlo[4], qhi[4];
  #pragma unroll
  for (int i = 0; i < 4; ++i) {
    qlo[i] = float4{0.f, 0.f, 0.f, 0.f};
    qhi[i] = float4{0.f, 0.f, 0.f, 0.f};
  }
  // prologue: issue kk=0..3 of first batch (in flight across LDS fill)
  {
    const int b0 = (bbase < Btot) ? bbase : 0;
    const float* Xc = X + (size_t)b0 * 3584 + lrow * 256 + lgrp * 8;
    if (rowok && bbase < Btot) {
      #pragma unroll
      for (int s = 0; s < 4; ++s) {
        qlo[s] = *(const float4*)(Xc + s * 32);
        qhi[s] = *(const float4*)(Xc + s * 32 + 4);
      }
    }
  }

  // ---- one-time LDS fill (read-only afterwards) ----
  #pragma unroll
  for (int i = 0; i < 8; ++i)
    WL1[i * 512 + tid] = ((const uint4*)wf)[i * 512 + tid];
  if (tid < 256) {
    const uint4* wf2 = (const uint4*)(wf + 32768);
    #pragma unroll
    for (int i = 0; i < 4; ++i)
      WL2[i * 256 + tid] = wf2[i * 256 + tid];
  }

  // ---- A_hat K16 B-fragment (k=14 row = 1 for bias injection) ----
  unsigned amx0, amx1;
  {
    float v[4];
    #pragma unroll
    for (int i = 0; i < 4; ++i) {
      const int k = lgrp * 4 + i;
      float s = 0.f;
      if (k == 14) s = 1.f;
      else if (k < 14 && rowok) {
        #pragma unroll
        for (int t = 0; t < 4; ++t)
          if (ADJ_IDX[k][t] == lrow) s += ADJ_W[k][t];
      }
      v[i] = s;
    }
    amx0 = pk2(v[0], v[1]);
    amx1 = pk2(v[2], v[3]);
  }
  const bf16x4 amx = mk4(amx0, amx1);

  unsigned b1p[4], b2p[2];
  #pragma unroll
  for (int i = 0; i < 4; ++i)
    b1p[i] = (unsigned)f2b(b1[(2 * i) * 16 + lrow]) |
             ((unsigned)f2b(b1[(2 * i + 1) * 16 + lrow]) << 16);
  #pragma unroll
  for (int i = 0; i < 2; ++i)
    b2p[i] = (unsigned)f2b(b2[(2 * i) * 16 + lrow]) |
             ((unsigned)f2b(b2[(2 * i + 1) * 16 + lrow]) << 16);
  const bool isg3 = (lgrp == 3);

  __syncthreads();   // the ONLY block-wide barrier

  const bf16x8* WL1v = (const bf16x8*)WL1;
  const f32x4 zacc = {0.f, 0.f, 0.f, 0.f};

  #pragma unroll
  for (int bi = 0; bi < NPW; ++bi) {
    const int b = bbase + bi;
    if (b >= Btot) break;   // wave-uniform
    const float* Xc = X + (size_t)b * 3584 + lrow * 256 + lgrp * 8;
    const bool pfn = (bi + 1 < NPW) && (b + 1 < Btot) && rowok;
    const float* Xn = X + (size_t)(b + 1) * 3584 + lrow * 256 + lgrp * 8;

    // ---------- GEMM1: G = Xb * W1; streaming X through rolling queue -------
    // slot kk&3: consume (cvt -> a), refill with kk+4 (same batch) or
    // next batch's kk-4 (cross-batch streaming).
    f32x4 acc1[8];
    #pragma unroll
    for (int nt = 0; nt < 8; ++nt) acc1[nt] = zacc;
    #pragma unroll
    for (int kk = 0; kk < 8; ++kk) {
      const int s = kk & 3;
      uint4 t;
      t.x = pk2(qlo[s].x, qlo[s].y);
      t.y = pk2(qlo[s].z, qlo[s].w);
      t.z = pk2(qhi[s].x, qhi[s].y);
      t.w = pk2(qhi[s].z, qhi[s].w);
      const bf16x8 a = __builtin_bit_cast(bf16x8, t);
      // refill the slot just consumed
      if (kk < 4) {
        if (rowok) {
          qlo[s] = *(const float4*)(Xc + (kk + 4) * 32);
          qhi[s] = *(const float4*)(Xc + (kk + 4) * 32 + 4);
        }
      } else {
        if (pfn) {
          qlo[s] = *(const float4*)(Xn + (kk - 4) * 32);
          qhi[s] = *(const float4*)(Xn + (kk - 4) * 32 + 4);
        }
      }
      #pragma unroll
      for (int nt = 0; nt < 8; ++nt)
        acc1[nt] = __builtin_amdgcn_mfma_f32_16x16x32_bf16(
            a, WL1v[(nt * 8 + kk) * 64 + lane], acc1[nt], 0, 0, 0);
    }

    // ---------- mix1: H1^T = G^T * Ahat_ext (K=16, lane-local A-frags) ------
    // acc1[mt][j] = G[node=4*lgrp+j][col=16*mt+lrow]
    unsigned h1p[8][2];
    #pragma unroll
    for (int mt = 0; mt < 8; ++mt) {
      const unsigned a0 = pk2(acc1[mt][0], acc1[mt][1]);
      const unsigned bw = (mt & 1) ? (b1p[mt >> 1] >> 16) : (b1p[mt >> 1] & 0xFFFFu);
      const unsigned a1 = isg3 ? bw : pk2(acc1[mt][2], acc1[mt][3]);
      const f32x4 h = MFMA16(mk4(a0, a1), amx, zacc);
      h1p[mt][0] = pk2(fmaxf(h[0], 0.f), fmaxf(h[1], 0.f));
      h1p[mt][1] = pk2(fmaxf(h[2], 0.f), fmaxf(h[3], 0.f));
    }

    // ---------- GEMM2: C2 = H1 * W2 (M16 x N64 x K128, 8 x K16) -------------
    f32x4 acc2[4];
    #pragma unroll
    for (int nt = 0; nt < 4; ++nt) acc2[nt] = zacc;
    #pragma unroll
    for (int kp = 0; kp < 4; ++kp) {
      const bf16x4 aE = mk4(h1p[2 * kp][0],     h1p[2 * kp][1]);
      const bf16x4 aO = mk4(h1p[2 * kp + 1][0], h1p[2 * kp + 1][1]);
      #pragma unroll
      for (int nt = 0; nt < 4; ++nt) {
        const uint4 w = WL2[(nt * 4 + kp) * 64 + lane];
        acc2[nt] = MFMA16(aE, mk4(w.x, w.y), acc2[nt]);
        acc2[nt] = MFMA16(aO, mk4(w.z, w.w), acc2[nt]);
      }
    }

    // ---------- mix2: out^T = C2^T * Ahat_ext (+b2 via k=14); store ---------
    float* outB = out + (size_t)b * 896;
    #pragma unroll
    for (int nt = 0; nt < 4; ++nt) {
      const unsigned a0 = pk2(acc2[nt][0], acc2[nt][1]);
      const unsigned bw = (nt & 1) ? (b2p[nt >> 1] >> 16) : (b2p[nt >> 1] & 0xFFFFu);
      const unsigned a1 = isg3 ? bw : pk2(acc2[nt][2], acc2[nt][3]);
      const f32x4 o = MFMA16(mk4(a0, a1), amx, zacc);
      if (rowok) {
        float4 st; st.x = o[0]; st.y = o[1]; st.z = o[2]; st.w = o[3];
        *(float4*)(outB + lrow * 64 + nt * 16 + lgrp * 4) = st;
      }
    }
  }
}

extern "C" void kernel_launch(void* const* d_in, const int* in_sizes, int n_in,
                              void* d_out, int out_size, void* d_ws, size_t ws_size,
                              hipStream_t stream) {
  (void)n_in; (void)out_size; (void)ws_size;
  const float* fea = (const float*)d_in[0];
  const float* W1  = (const float*)d_in[1];
  const float* b1  = (const float*)d_in[2];
  const float* W2  = (const float*)d_in[3];
  const float* b2  = (const float*)d_in[4];
  float* out = (float*)d_out;
  const int Btot = in_sizes[0] / (14 * 256);

  unsigned short* wf = (unsigned short*)d_ws;    // needs 80 KiB of d_ws
  prep_w<<<20, 256, 0, stream>>>(W1, W2, wf);

  const int per_block = 8 * NPW;
  const int grid = (Btot + per_block - 1) / per_block;
  fpm_kernel<<<grid, 512, 0, stream>>>(fea, wf, b1, b2, out, Btot);
}

// Round 18
// 63.105 us; speedup vs baseline: 1.4772x; 1.4772x over previous
//
#include <hip/hip_runtime.h>
#include <hip/hip_bf16.h>

typedef __attribute__((ext_vector_type(8))) short bf16x8;
typedef __attribute__((ext_vector_type(4))) short bf16x4;
typedef __attribute__((ext_vector_type(4))) float f32x4;

#define NPW 4   // batches per wave

#define A3  0.33333334f
#define B4  0.25f
#define C34 0.28867513f

__device__ const int ADJ_IDX[16][4] = {
  {0,1,7,0},{1,0,2,8},{2,1,3,9},{3,2,4,10},
  {4,3,5,11},{5,4,6,12},{6,5,13,0},{7,0,8,0},
  {8,7,9,1},{9,8,10,2},{10,9,11,3},{11,10,12,4},
  {12,11,13,5},{13,12,6,0},{0,0,0,0},{0,0,0,0}
};
__device__ const float ADJ_W[16][4] = {
  {A3,C34,A3,0.f},{B4,C34,B4,B4},{B4,B4,B4,B4},{B4,B4,B4,B4},
  {B4,B4,B4,B4},{B4,B4,C34,B4},{A3,C34,A3,0.f},{A3,A3,C34,0.f},
  {B4,C34,B4,B4},{B4,B4,B4,B4},{B4,B4,B4,B4},{B4,B4,B4,B4},
  {B4,B4,C34,B4},{A3,C34,A3,0.f},{0.f,0.f,0.f,0.f},{0.f,0.f,0.f,0.f}
};

__device__ __forceinline__ unsigned short f2b(float x) {
  unsigned u = __builtin_bit_cast(unsigned, x);
  u += 0x7FFFu + ((u >> 16) & 1u);   // RNE bf16
  return (unsigned short)(u >> 16);
}
__device__ __forceinline__ unsigned pk2(float lo, float hi) {
  float2 t; t.x = lo; t.y = hi;
  __hip_bfloat162 h = __float22bfloat162_rn(t);
  unsigned u; __builtin_memcpy(&u, &h, 4);
  return u;
}
__device__ __forceinline__ bf16x4 mk4(unsigned lo, unsigned hi) {
  uint2 u; u.x = lo; u.y = hi;
  return __builtin_bit_cast(bf16x4, u);
}

#if __has_builtin(__builtin_amdgcn_mfma_f32_16x16x16_bf16)
#define MFMA16(a, b, c) __builtin_amdgcn_mfma_f32_16x16x16_bf16((a), (b), (c), 0, 0, 0)
#elif __has_builtin(__builtin_amdgcn_mfma_f32_16x16x16bf16_1k)
#define MFMA16(a, b, c) __builtin_amdgcn_mfma_f32_16x16x16bf16_1k((a), (b), (c), 0, 0, 0)
#else
__device__ __forceinline__ f32x4 mfma16_asm(bf16x4 a, bf16x4 b, f32x4 c) {
  f32x4 d;
  asm("v_mfma_f32_16x16x16_bf16 %0, %1, %2, %3\n\ts_nop 7\n\ts_nop 7"
      : "=v"(d) : "v"(a), "v"(b), "v"(c));
  return d;
}
#define MFMA16(a, b, c) mfma16_asm((a), (b), (c))
#endif

// ---------- weight prep (layouts unchanged) ----------
__global__ __launch_bounds__(256) void prep_w(
    const float* __restrict__ W1, const float* __restrict__ W2,
    unsigned short* __restrict__ wf)
{
  const int f = blockIdx.x * 256 + threadIdx.x;   // 20 blocks -> 5120
  if (f < 4096) {
    const int lane = f & 63, kk = (f >> 6) & 7, nt = f >> 9;
    const int col = nt * 16 + (lane & 15);
    const int k0  = kk * 32 + (lane >> 4) * 8;
    unsigned short tmp[8];
    #pragma unroll
    for (int j = 0; j < 8; ++j) tmp[j] = f2b(W1[(k0 + j) * 128 + col]);
    *(uint4*)(wf + (size_t)f * 8) = *(const uint4*)tmp;
  } else if (f < 5120) {
    const int f2i = f - 4096;                     // 0..1023
    const int lane = f2i & 63, kp = (f2i >> 6) & 3, nt = f2i >> 8;
    const int col = nt * 16 + (lane & 15);
    const int k0  = kp * 32 + (lane >> 4) * 4;
    uint4 q;
    q.x = (unsigned)f2b(W2[(k0 + 0) * 64 + col]) | ((unsigned)f2b(W2[(k0 + 1) * 64 + col]) << 16);
    q.y = (unsigned)f2b(W2[(k0 + 2) * 64 + col]) | ((unsigned)f2b(W2[(k0 + 3) * 64 + col]) << 16);
    q.z = (unsigned)f2b(W2[(k0 + 16) * 64 + col]) | ((unsigned)f2b(W2[(k0 + 17) * 64 + col]) << 16);
    q.w = (unsigned)f2b(W2[(k0 + 18) * 64 + col]) | ((unsigned)f2b(W2[(k0 + 19) * 64 + col]) << 16);
    *(uint4*)(wf + 32768 + (size_t)f2i * 8) = q;
  }
}

__global__ __launch_bounds__(512, 4) void fpm_kernel(
    const float* __restrict__ X,
    const unsigned short* __restrict__ wf,
    const float* __restrict__ b1, const float* __restrict__ b2,
    float* __restrict__ out, int Btot)
{
  __shared__ __align__(16) uint4 WL1[4096];   // 64 KiB W1 frags
  __shared__ __align__(16) uint4 WL2[1024];   // 16 KiB paired W2 frags
  // 80 KiB total: 2 blocks/CU co-reside when regs fit (R14: occ 43%)

  const int tid  = threadIdx.x;
  const int lane = tid & 63;
  const int wv   = tid >> 6;
  const int lrow = lane & 15;
  const int lgrp = lane >> 4;

  const int gw    = blockIdx.x * 8 + wv;
  const int bbase = gw * NPW;
  const bool rowok = (lrow < 14);

  // ---- rolling X queue: DEPTH 2 (16 f32 regs) ----
  float4 qlo[2], qhi[2];
  #pragma unroll
  for (int i = 0; i < 2; ++i) {
    qlo[i] = float4{0.f, 0.f, 0.f, 0.f};
    qhi[i] = float4{0.f, 0.f, 0.f, 0.f};
  }
  // prologue: issue kk=0,1 of first batch (in flight across LDS fill)
  {
    const int b0 = (bbase < Btot) ? bbase : 0;
    const float* Xc = X + (size_t)b0 * 3584 + lrow * 256 + lgrp * 8;
    if (rowok && bbase < Btot) {
      #pragma unroll
      for (int s = 0; s < 2; ++s) {
        qlo[s] = *(const float4*)(Xc + s * 32);
        qhi[s] = *(const float4*)(Xc + s * 32 + 4);
      }
    }
  }

  // ---- one-time LDS fill (read-only afterwards) ----
  #pragma unroll
  for (int i = 0; i < 8; ++i)
    WL1[i * 512 + tid] = ((const uint4*)wf)[i * 512 + tid];
  if (tid < 256) {
    const uint4* wf2 = (const uint4*)(wf + 32768);
    #pragma unroll
    for (int i = 0; i < 4; ++i)
      WL2[i * 256 + tid] = wf2[i * 256 + tid];
  }

  // ---- A_hat K16 B-fragment (k=14 row = 1 for bias injection) ----
  unsigned amx0, amx1;
  {
    float v[4];
    #pragma unroll
    for (int i = 0; i < 4; ++i) {
      const int k = lgrp * 4 + i;
      float s = 0.f;
      if (k == 14) s = 1.f;
      else if (k < 14 && rowok) {
        #pragma unroll
        for (int t = 0; t < 4; ++t)
          if (ADJ_IDX[k][t] == lrow) s += ADJ_W[k][t];
      }
      v[i] = s;
    }
    amx0 = pk2(v[0], v[1]);
    amx1 = pk2(v[2], v[3]);
  }
  const bf16x4 amx = mk4(amx0, amx1);

  unsigned b1p[4], b2p[2];
  #pragma unroll
  for (int i = 0; i < 4; ++i)
    b1p[i] = (unsigned)f2b(b1[(2 * i) * 16 + lrow]) |
             ((unsigned)f2b(b1[(2 * i + 1) * 16 + lrow]) << 16);
  #pragma unroll
  for (int i = 0; i < 2; ++i)
    b2p[i] = (unsigned)f2b(b2[(2 * i) * 16 + lrow]) |
             ((unsigned)f2b(b2[(2 * i + 1) * 16 + lrow]) << 16);
  const bool isg3 = (lgrp == 3);

  __syncthreads();   // the ONLY block-wide barrier

  const bf16x8* WL1v = (const bf16x8*)WL1;
  const f32x4 zacc = {0.f, 0.f, 0.f, 0.f};

  for (int bi = 0; bi < NPW; ++bi) {
    const int b = bbase + bi;
    if (b >= Btot) break;   // wave-uniform
    const float* Xc = X + (size_t)b * 3584 + lrow * 256 + lgrp * 8;
    const bool pfn = (bi + 1 < NPW) && (b + 1 < Btot) && rowok;

    // ---------- GEMM1: G = Xb * W1; X streamed through depth-2 queue --------
    // slot kk&1: consume (cvt -> a), refill with kk+2 (same batch for kk<6,
    // next batch's kk-6 for kk>=6 -> seamless cross-batch streaming).
    f32x4 acc1[8];
    #pragma unroll
    for (int nt = 0; nt < 8; ++nt) acc1[nt] = zacc;
    #pragma unroll
    for (int kk = 0; kk < 8; ++kk) {
      const int s = kk & 1;
      uint4 t;
      t.x = pk2(qlo[s].x, qlo[s].y);
      t.y = pk2(qlo[s].z, qlo[s].w);
      t.z = pk2(qhi[s].x, qhi[s].y);
      t.w = pk2(qhi[s].z, qhi[s].w);
      const bf16x8 a = __builtin_bit_cast(bf16x8, t);
      // refill the slot just consumed
      if (kk < 6) {
        if (rowok) {
          qlo[s] = *(const float4*)(Xc + (kk + 2) * 32);
          qhi[s] = *(const float4*)(Xc + (kk + 2) * 32 + 4);
        }
      } else {
        if (pfn) {
          qlo[s] = *(const float4*)(Xc + 3584 + (kk - 6) * 32);
          qhi[s] = *(const float4*)(Xc + 3584 + (kk - 6) * 32 + 4);
        }
      }
      #pragma unroll
      for (int nt = 0; nt < 8; ++nt)
        acc1[nt] = __builtin_amdgcn_mfma_f32_16x16x32_bf16(
            a, WL1v[(nt * 8 + kk) * 64 + lane], acc1[nt], 0, 0, 0);
    }

    // ---------- mix1: H1^T = G^T * Ahat_ext (K=16, lane-local A-frags) ------
    unsigned h1p[8][2];
    #pragma unroll
    for (int mt = 0; mt < 8; ++mt) {
      const unsigned a0 = pk2(acc1[mt][0], acc1[mt][1]);
      const unsigned bw = (mt & 1) ? (b1p[mt >> 1] >> 16) : (b1p[mt >> 1] & 0xFFFFu);
      const unsigned a1 = isg3 ? bw : pk2(acc1[mt][2], acc1[mt][3]);
      const f32x4 h = MFMA16(mk4(a0, a1), amx, zacc);
      h1p[mt][0] = pk2(fmaxf(h[0], 0.f), fmaxf(h[1], 0.f));
      h1p[mt][1] = pk2(fmaxf(h[2], 0.f), fmaxf(h[3], 0.f));
    }

    // ---------- GEMM2: C2 = H1 * W2 (M16 x N64 x K128, 8 x K16) -------------
    f32x4 acc2[4];
    #pragma unroll
    for (int nt = 0; nt < 4; ++nt) acc2[nt] = zacc;
    #pragma unroll
    for (int kp = 0; kp < 4; ++kp) {
      const bf16x4 aE = mk4(h1p[2 * kp][0],     h1p[2 * kp][1]);
      const bf16x4 aO = mk4(h1p[2 * kp + 1][0], h1p[2 * kp + 1][1]);
      #pragma unroll
      for (int nt = 0; nt < 4; ++nt) {
        const uint4 w = WL2[(nt * 4 + kp) * 64 + lane];
        acc2[nt] = MFMA16(aE, mk4(w.x, w.y), acc2[nt]);
        acc2[nt] = MFMA16(aO, mk4(w.z, w.w), acc2[nt]);
      }
    }

    // ---------- mix2: out^T = C2^T * Ahat_ext (+b2 via k=14); store ---------
    float* outB = out + (size_t)b * 896;
    #pragma unroll
    for (int nt = 0; nt < 4; ++nt) {
      const unsigned a0 = pk2(acc2[nt][0], acc2[nt][1]);
      const unsigned bw = (nt & 1) ? (b2p[nt >> 1] >> 16) : (b2p[nt >> 1] & 0xFFFFu);
      const unsigned a1 = isg3 ? bw : pk2(acc2[nt][2], acc2[nt][3]);
      const f32x4 o = MFMA16(mk4(a0, a1), amx, zacc);
      if (rowok) {
        float4 st; st.x = o[0]; st.y = o[1]; st.z = o[2]; st.w = o[3];
        *(float4*)(outB + lrow * 64 + nt * 16 + lgrp * 4) = st;
      }
    }
  }
}

extern "C" void kernel_launch(void* const* d_in, const int* in_sizes, int n_in,
                              void* d_out, int out_size, void* d_ws, size_t ws_size,
                              hipStream_t stream) {
  (void)n_in; (void)out_size; (void)ws_size;
  const float* fea = (const float*)d_in[0];
  const float* W1  = (const float*)d_in[1];
  const float* b1  = (const float*)d_in[2];
  const float* W2  = (const float*)d_in[3];
  const float* b2  = (const float*)d_in[4];
  float* out = (float*)d_out;
  const int Btot = in_sizes[0] / (14 * 256);

  unsigned short* wf = (unsigned short*)d_ws;    // needs 80 KiB of d_ws
  prep_w<<<20, 256, 0, stream>>>(W1, W2, wf);

  const int per_block = 8 * NPW;
  const int grid = (Btot + per_block - 1) / per_block;
  fpm_kernel<<<grid, 512, 0, stream>>>(fea, wf, b1, b2, out, Btot);
}

// Round 19
// 60.890 us; speedup vs baseline: 1.5309x; 1.0364x over previous
//
#include <hip/hip_runtime.h>
#include <hip/hip_bf16.h>

typedef __attribute__((ext_vector_type(8))) short bf16x8;
typedef __attribute__((ext_vector_type(4))) short bf16x4;
typedef __attribute__((ext_vector_type(4))) float f32x4;

#define NPW 4   // batches per wave

#define A3  0.33333334f
#define B4  0.25f
#define C34 0.28867513f

__device__ const int ADJ_IDX[16][4] = {
  {0,1,7,0},{1,0,2,8},{2,1,3,9},{3,2,4,10},
  {4,3,5,11},{5,4,6,12},{6,5,13,0},{7,0,8,0},
  {8,7,9,1},{9,8,10,2},{10,9,11,3},{11,10,12,4},
  {12,11,13,5},{13,12,6,0},{0,0,0,0},{0,0,0,0}
};
__device__ const float ADJ_W[16][4] = {
  {A3,C34,A3,0.f},{B4,C34,B4,B4},{B4,B4,B4,B4},{B4,B4,B4,B4},
  {B4,B4,B4,B4},{B4,B4,C34,B4},{A3,C34,A3,0.f},{A3,A3,C34,0.f},
  {B4,C34,B4,B4},{B4,B4,B4,B4},{B4,B4,B4,B4},{B4,B4,B4,B4},
  {B4,B4,C34,B4},{A3,C34,A3,0.f},{0.f,0.f,0.f,0.f},{0.f,0.f,0.f,0.f}
};

__device__ __forceinline__ unsigned short f2b(float x) {
  unsigned u = __builtin_bit_cast(unsigned, x);
  u += 0x7FFFu + ((u >> 16) & 1u);   // RNE bf16
  return (unsigned short)(u >> 16);
}
__device__ __forceinline__ unsigned pk2(float lo, float hi) {
  float2 t; t.x = lo; t.y = hi;
  __hip_bfloat162 h = __float22bfloat162_rn(t);
  unsigned u; __builtin_memcpy(&u, &h, 4);
  return u;
}
__device__ __forceinline__ bf16x4 mk4(unsigned lo, unsigned hi) {
  uint2 u; u.x = lo; u.y = hi;
  return __builtin_bit_cast(bf16x4, u);
}

#if __has_builtin(__builtin_amdgcn_mfma_f32_16x16x16_bf16)
#define MFMA16(a, b, c) __builtin_amdgcn_mfma_f32_16x16x16_bf16((a), (b), (c), 0, 0, 0)
#elif __has_builtin(__builtin_amdgcn_mfma_f32_16x16x16bf16_1k)
#define MFMA16(a, b, c) __builtin_amdgcn_mfma_f32_16x16x16bf16_1k((a), (b), (c), 0, 0, 0)
#else
__device__ __forceinline__ f32x4 mfma16_asm(bf16x4 a, bf16x4 b, f32x4 c) {
  f32x4 d;
  asm("v_mfma_f32_16x16x16_bf16 %0, %1, %2, %3\n\ts_nop 7\n\ts_nop 7"
      : "=v"(d) : "v"(a), "v"(b), "v"(c));
  return d;
}
#define MFMA16(a, b, c) mfma16_asm((a), (b), (c))
#endif

__global__ __launch_bounds__(512, 4) void fpm_kernel(
    const float* __restrict__ X,
    const float* __restrict__ W1, const float* __restrict__ W2,
    const float* __restrict__ b1, const float* __restrict__ b2,
    float* __restrict__ out, int Btot)
{
  __shared__ __align__(16) uint4 WL1[4096];   // 64 KiB W1 frags
  __shared__ __align__(16) uint4 WL2[1024];   // 16 KiB paired W2 frags
  // 80 KiB total: 2 blocks/CU co-reside when regs fit (R14/R18: occ ~43%)

  const int tid  = threadIdx.x;
  const int lane = tid & 63;
  const int wv   = tid >> 6;
  const int lrow = lane & 15;
  const int lgrp = lane >> 4;

  const int gw    = blockIdx.x * 8 + wv;
  const int bbase = gw * NPW;
  const bool rowok = (lrow < 14);

  // ---- rolling X queue: DEPTH 2 (16 f32 regs) ----
  float4 qlo[2], qhi[2];
  #pragma unroll
  for (int i = 0; i < 2; ++i) {
    qlo[i] = float4{0.f, 0.f, 0.f, 0.f};
    qhi[i] = float4{0.f, 0.f, 0.f, 0.f};
  }
  // prologue: issue kk=0,1 of first batch (in flight across weight fill)
  {
    const int b0 = (bbase < Btot) ? bbase : 0;
    const float* Xc = X + (size_t)b0 * 3584 + lrow * 256 + lgrp * 8;
    if (rowok && bbase < Btot) {
      #pragma unroll
      for (int s = 0; s < 2; ++s) {
        qlo[s] = *(const float4*)(Xc + s * 32);
        qhi[s] = *(const float4*)(Xc + s * 32 + 4);
      }
    }
  }

  // ---- in-kernel weight fragment build (was prep_w; folds the extra
  //      kernel+launch into the prologue, hidden under X-load latency;
  //      W1/W2 are L2-broadcast-hot across the 512 blocks) ----
  // W1 (K=32 B-frags): frag (nt*8+kk); lane holds W1[kk*32+lgrp*8+j][nt*16+lrow]
  #pragma unroll 2
  for (int i = 0; i < 8; ++i) {
    const int f  = i * 512 + tid;
    const int fl = f & 63, kk = (f >> 6) & 7, nt = f >> 9;
    const int col = nt * 16 + (fl & 15);
    const int k0  = kk * 32 + (fl >> 4) * 8;
    uint4 q;
    q.x = pk2(W1[(k0 + 0) * 128 + col], W1[(k0 + 1) * 128 + col]);
    q.y = pk2(W1[(k0 + 2) * 128 + col], W1[(k0 + 3) * 128 + col]);
    q.z = pk2(W1[(k0 + 4) * 128 + col], W1[(k0 + 5) * 128 + col]);
    q.w = pk2(W1[(k0 + 6) * 128 + col], W1[(k0 + 7) * 128 + col]);
    WL1[f] = q;
  }
  // W2 (K=16 B-frags, PAIRED): uint4 (nt*4+kp)*64+lane holds kt2=2kp (xy),
  // kt2=2kp+1 (zw): W2[kt2*16+lgrp*4+i][nt*16+lrow]
  #pragma unroll
  for (int i = 0; i < 2; ++i) {
    const int g  = i * 512 + tid;
    const int gl = g & 63, kp = (g >> 6) & 3, nt = g >> 8;
    const int col = nt * 16 + (gl & 15);
    const int k0  = kp * 32 + (gl >> 4) * 4;
    uint4 q;
    q.x = pk2(W2[(k0 + 0) * 64 + col],  W2[(k0 + 1) * 64 + col]);
    q.y = pk2(W2[(k0 + 2) * 64 + col],  W2[(k0 + 3) * 64 + col]);
    q.z = pk2(W2[(k0 + 16) * 64 + col], W2[(k0 + 17) * 64 + col]);
    q.w = pk2(W2[(k0 + 18) * 64 + col], W2[(k0 + 19) * 64 + col]);
    WL2[g] = q;
  }

  // ---- A_hat K16 B-fragment (k=14 row = 1 for bias injection) ----
  unsigned amx0, amx1;
  {
    float v[4];
    #pragma unroll
    for (int i = 0; i < 4; ++i) {
      const int k = lgrp * 4 + i;
      float s = 0.f;
      if (k == 14) s = 1.f;
      else if (k < 14 && rowok) {
        #pragma unroll
        for (int t = 0; t < 4; ++t)
          if (ADJ_IDX[k][t] == lrow) s += ADJ_W[k][t];
      }
      v[i] = s;
    }
    amx0 = pk2(v[0], v[1]);
    amx1 = pk2(v[2], v[3]);
  }
  const bf16x4 amx = mk4(amx0, amx1);

  unsigned b1p[4], b2p[2];
  #pragma unroll
  for (int i = 0; i < 4; ++i)
    b1p[i] = (unsigned)f2b(b1[(2 * i) * 16 + lrow]) |
             ((unsigned)f2b(b1[(2 * i + 1) * 16 + lrow]) << 16);
  #pragma unroll
  for (int i = 0; i < 2; ++i)
    b2p[i] = (unsigned)f2b(b2[(2 * i) * 16 + lrow]) |
             ((unsigned)f2b(b2[(2 * i + 1) * 16 + lrow]) << 16);
  const bool isg3 = (lgrp == 3);

  __syncthreads();   // the ONLY block-wide barrier

  const bf16x8* WL1v = (const bf16x8*)WL1;
  const f32x4 zacc = {0.f, 0.f, 0.f, 0.f};

  for (int bi = 0; bi < NPW; ++bi) {
    const int b = bbase + bi;
    if (b >= Btot) break;   // wave-uniform
    const float* Xc = X + (size_t)b * 3584 + lrow * 256 + lgrp * 8;
    const bool pfn = (bi + 1 < NPW) && (b + 1 < Btot) && rowok;

    // ---------- GEMM1: G = Xb * W1; X streamed through depth-2 queue --------
    // slot kk&1: consume (cvt -> a), refill with kk+2 (same batch for kk<6,
    // next batch's kk-6 for kk>=6 -> seamless cross-batch streaming).
    f32x4 acc1[8];
    #pragma unroll
    for (int nt = 0; nt < 8; ++nt) acc1[nt] = zacc;
    #pragma unroll
    for (int kk = 0; kk < 8; ++kk) {
      const int s = kk & 1;
      uint4 t;
      t.x = pk2(qlo[s].x, qlo[s].y);
      t.y = pk2(qlo[s].z, qlo[s].w);
      t.z = pk2(qhi[s].x, qhi[s].y);
      t.w = pk2(qhi[s].z, qhi[s].w);
      const bf16x8 a = __builtin_bit_cast(bf16x8, t);
      // refill the slot just consumed
      if (kk < 6) {
        if (rowok) {
          qlo[s] = *(const float4*)(Xc + (kk + 2) * 32);
          qhi[s] = *(const float4*)(Xc + (kk + 2) * 32 + 4);
        }
      } else {
        if (pfn) {
          qlo[s] = *(const float4*)(Xc + 3584 + (kk - 6) * 32);
          qhi[s] = *(const float4*)(Xc + 3584 + (kk - 6) * 32 + 4);
        }
      }
      #pragma unroll
      for (int nt = 0; nt < 8; ++nt)
        acc1[nt] = __builtin_amdgcn_mfma_f32_16x16x32_bf16(
            a, WL1v[(nt * 8 + kk) * 64 + lane], acc1[nt], 0, 0, 0);
    }

    // ---------- mix1: H1^T = G^T * Ahat_ext (K=16, lane-local A-frags) ------
    unsigned h1p[8][2];
    #pragma unroll
    for (int mt = 0; mt < 8; ++mt) {
      const unsigned a0 = pk2(acc1[mt][0], acc1[mt][1]);
      const unsigned bw = (mt & 1) ? (b1p[mt >> 1] >> 16) : (b1p[mt >> 1] & 0xFFFFu);
      const unsigned a1 = isg3 ? bw : pk2(acc1[mt][2], acc1[mt][3]);
      const f32x4 h = MFMA16(mk4(a0, a1), amx, zacc);
      h1p[mt][0] = pk2(fmaxf(h[0], 0.f), fmaxf(h[1], 0.f));
      h1p[mt][1] = pk2(fmaxf(h[2], 0.f), fmaxf(h[3], 0.f));
    }

    // ---------- GEMM2: C2 = H1 * W2 (M16 x N64 x K128, 8 x K16) -------------
    f32x4 acc2[4];
    #pragma unroll
    for (int nt = 0; nt < 4; ++nt) acc2[nt] = zacc;
    #pragma unroll
    for (int kp = 0; kp < 4; ++kp) {
      const bf16x4 aE = mk4(h1p[2 * kp][0],     h1p[2 * kp][1]);
      const bf16x4 aO = mk4(h1p[2 * kp + 1][0], h1p[2 * kp + 1][1]);
      #pragma unroll
      for (int nt = 0; nt < 4; ++nt) {
        const uint4 w = WL2[(nt * 4 + kp) * 64 + lane];
        acc2[nt] = MFMA16(aE, mk4(w.x, w.y), acc2[nt]);
        acc2[nt] = MFMA16(aO, mk4(w.z, w.w), acc2[nt]);
      }
    }

    // ---------- mix2: out^T = C2^T * Ahat_ext (+b2 via k=14); store ---------
    float* outB = out + (size_t)b * 896;
    #pragma unroll
    for (int nt = 0; nt < 4; ++nt) {
      const unsigned a0 = pk2(acc2[nt][0], acc2[nt][1]);
      const unsigned bw = (nt & 1) ? (b2p[nt >> 1] >> 16) : (b2p[nt >> 1] & 0xFFFFu);
      const unsigned a1 = isg3 ? bw : pk2(acc2[nt][2], acc2[nt][3]);
      const f32x4 o = MFMA16(mk4(a0, a1), amx, zacc);
      if (rowok) {
        float4 st; st.x = o[0]; st.y = o[1]; st.z = o[2]; st.w = o[3];
        *(float4*)(outB + lrow * 64 + nt * 16 + lgrp * 4) = st;
      }
    }
  }
}

extern "C" void kernel_launch(void* const* d_in, const int* in_sizes, int n_in,
                              void* d_out, int out_size, void* d_ws, size_t ws_size,
                              hipStream_t stream) {
  (void)n_in; (void)out_size; (void)d_ws; (void)ws_size;
  const float* fea = (const float*)d_in[0];
  const float* W1  = (const float*)d_in[1];
  const float* b1  = (const float*)d_in[2];
  const float* W2  = (const float*)d_in[3];
  const float* b2  = (const float*)d_in[4];
  float* out = (float*)d_out;
  const int Btot = in_sizes[0] / (14 * 256);

  const int per_block = 8 * NPW;
  const int grid = (Btot + per_block - 1) / per_block;
  fpm_kernel<<<grid, 512, 0, stream>>>(fea, W1, W2, b1, b2, out, Btot);
}